// Round 1
// baseline (448.588 us; speedup 1.0000x reference)
//
#include <hip/hip_runtime.h>

// SelfAttention block: GroupNorm -> 1x1 QKV -> softmax attention over HW=1024 -> 1x1 proj + residual
// B=16, C=512, H=W=32 (HW=1024), GROUPS=32, EPS=1e-5, scale=C^-0.5
//
// Round 0: correctness-first MFMA (f16 in, fp32 acc) pipeline, 6 dispatches.

typedef _Float16 f16;
typedef _Float16 f16x8 __attribute__((ext_vector_type(8)));
typedef _Float16 f16x4 __attribute__((ext_vector_type(4)));
typedef float fx4 __attribute__((ext_vector_type(4)));

#define BM 64
#define BN 64
#define BK 32
#define LDK (BK + 8)   // padded LDS leading dim: stride 80B -> 2-way-max bank aliasing on b128 reads

// ---------------- GroupNorm: x fp32 [16][512][1024] -> xn f16, per (b,g) block ----------------
__global__ __launch_bounds__(256)
void groupnorm_kernel(const float* __restrict__ x, const float* __restrict__ gamma,
                      const float* __restrict__ beta, f16* __restrict__ xn)
{
    __shared__ float red[256], red2[256];
    __shared__ float mu_s, rs_s;
    const int blk = blockIdx.x;              // b*32 + g
    const int g = blk & 31;
    const long base = (long)blk * (16 * 1024);   // 16 channels * 1024 spatial per group
    const int tid = threadIdx.x;
    const float4* xv = (const float4*)(x + base);

    float s = 0.f, s2 = 0.f;
#pragma unroll
    for (int i = 0; i < 16; i++) {
        float4 v = xv[tid + i * 256];
        s  += v.x + v.y + v.z + v.w;
        s2 += v.x * v.x + v.y * v.y + v.z * v.z + v.w * v.w;
    }
    red[tid] = s; red2[tid] = s2;
    __syncthreads();
    for (int off = 128; off > 0; off >>= 1) {
        if (tid < off) { red[tid] += red[tid + off]; red2[tid] += red2[tid + off]; }
        __syncthreads();
    }
    if (tid == 0) {
        float mu = red[0] * (1.f / 16384.f);
        float var = red2[0] * (1.f / 16384.f) - mu * mu;
        mu_s = mu;
        rs_s = rsqrtf(var + 1e-5f);
    }
    __syncthreads();
    const float mu = mu_s, rs = rs_s;

#pragma unroll
    for (int i = 0; i < 16; i++) {
        int e4 = tid + i * 256;
        float4 v = xv[e4];
        int e = e4 * 4;
        int ch = g * 16 + (e >> 10);         // 4 consecutive elems share a channel (1024 % 4 == 0)
        float gm = gamma[ch] * rs;
        float bt = beta[ch] - mu * gm;
        f16x4 o;
        o[0] = (f16)(v.x * gm + bt);
        o[1] = (f16)(v.y * gm + bt);
        o[2] = (f16)(v.z * gm + bt);
        o[3] = (f16)(v.w * gm + bt);
        *(f16x4*)(xn + base + e) = o;
    }
}

// ---------------- Row softmax over j: S f16 [16][1024][1024], one wave per row ----------------
__global__ __launch_bounds__(256)
void softmax_kernel(f16* __restrict__ S)
{
    const int wid = blockIdx.x * 4 + (threadIdx.x >> 6);   // row id, 0..16383
    const int lane = threadIdx.x & 63;
    f16* p = S + (long)wid * 1024 + lane * 16;             // 16 contiguous per lane
    f16x8 h0 = *(const f16x8*)p;
    f16x8 h1 = *(const f16x8*)(p + 8);
    float v[16];
#pragma unroll
    for (int i = 0; i < 8; i++) { v[i] = (float)h0[i]; v[8 + i] = (float)h1[i]; }
    float mx = v[0];
#pragma unroll
    for (int i = 1; i < 16; i++) mx = fmaxf(mx, v[i]);
    for (int off = 32; off > 0; off >>= 1) mx = fmaxf(mx, __shfl_xor(mx, off, 64));
    float sum = 0.f;
#pragma unroll
    for (int i = 0; i < 16; i++) { v[i] = __expf(v[i] - mx); sum += v[i]; }
    for (int off = 32; off > 0; off >>= 1) sum += __shfl_xor(sum, off, 64);
    const float inv = 1.f / sum;
#pragma unroll
    for (int i = 0; i < 8; i++) { h0[i] = (f16)(v[i] * inv); h1[i] = (f16)(v[8 + i] * inv); }
    *(f16x8*)p = h0;
    *(f16x8*)(p + 8) = h1;
}

// ---------------- Generic 64x64 MFMA GEMM, C[M][N] = alpha * A(MxK) * B(KxN) (+bias)(+resid) ----
// A_T:   A stored [K][M] (lda = stride between k rows), else [M][K] (lda = stride between m rows)
// B_T:   B stored [N][K] (ldb = stride between n rows), else [K][N] (ldb = stride between k rows)
template<bool A_F32, bool A_T, bool B_T, bool OUT_F32, bool HAS_BIAS, bool HAS_RESID>
__global__ __launch_bounds__(256)
void gemm_mfma(const void* __restrict__ Ap_, const f16* __restrict__ Bp_,
               void* __restrict__ Cp_, const float* __restrict__ bias,
               const float* __restrict__ resid, float alpha,
               int M, int N, int K, int lda, int ldb,
               long sAb, long sBb, long sCb)
{
    __shared__ __align__(16) f16 As[BM][LDK];   // As[m][k]
    __shared__ __align__(16) f16 Bs[BN][LDK];   // Bs[n][k]

    const int b = blockIdx.z;
    const f16* Bp = Bp_ + (long)b * sBb;
    const int m0 = blockIdx.y * BM, n0 = blockIdx.x * BN;
    const int tid = threadIdx.x;
    const int wave = tid >> 6, lane = tid & 63;
    const int quad = lane >> 4, l15 = lane & 15;
    const int wm = (wave >> 1) * 32, wn = (wave & 1) * 32;

    fx4 acc[2][2] = {};

    for (int k0 = 0; k0 < K; k0 += BK) {
        // ---- stage A tile -> As[m][k]
        if (!A_T) {
            int m = tid >> 2;
            int kk = (tid & 3) * 8;
            if (A_F32) {
                const float* A = (const float*)Ap_ + (long)b * sAb;
                const float* src = A + (long)(m0 + m) * lda + k0 + kk;
                float4 f0 = *(const float4*)src;
                float4 f1 = *(const float4*)(src + 4);
                f16x8 o;
                o[0]=(f16)f0.x; o[1]=(f16)f0.y; o[2]=(f16)f0.z; o[3]=(f16)f0.w;
                o[4]=(f16)f1.x; o[5]=(f16)f1.y; o[6]=(f16)f1.z; o[7]=(f16)f1.w;
                *(f16x8*)&As[m][kk] = o;
            } else {
                const f16* A = (const f16*)Ap_ + (long)b * sAb;
                *(f16x8*)&As[m][kk] = *(const f16x8*)(A + (long)(m0 + m) * lda + k0 + kk);
            }
        } else {
            // stored [K][M], contiguous in m -> transpose into As
            const f16* A = (const f16*)Ap_ + (long)b * sAb;
            int kk = tid >> 3;
            int m = (tid & 7) * 8;
            f16x8 t = *(const f16x8*)(A + (long)(k0 + kk) * lda + m0 + m);
#pragma unroll
            for (int j = 0; j < 8; j++) As[m + j][kk] = t[j];
        }
        // ---- stage B tile -> Bs[n][k]
        if (!B_T) {
            // stored [K][N], contiguous in n -> transpose into Bs
            int kk = tid >> 3;
            int n = (tid & 7) * 8;
            f16x8 t = *(const f16x8*)(Bp + (long)(k0 + kk) * ldb + n0 + n);
#pragma unroll
            for (int j = 0; j < 8; j++) Bs[n + j][kk] = t[j];
        } else {
            // stored [N][K], contiguous in k -> direct copy
            int n = tid >> 2;
            int kk = (tid & 3) * 8;
            *(f16x8*)&Bs[n][kk] = *(const f16x8*)(Bp + (long)(n0 + n) * ldb + k0 + kk);
        }
        __syncthreads();

        // ---- MFMA: A frag = A[m=l15][k=quad*8+j], B frag = B[k=quad*8+j][n=l15]
        f16x8 a0 = *(const f16x8*)&As[wm +  0 + l15][quad * 8];
        f16x8 a1 = *(const f16x8*)&As[wm + 16 + l15][quad * 8];
        f16x8 b0 = *(const f16x8*)&Bs[wn +  0 + l15][quad * 8];
        f16x8 b1 = *(const f16x8*)&Bs[wn + 16 + l15][quad * 8];
        acc[0][0] = __builtin_amdgcn_mfma_f32_16x16x32_f16(a0, b0, acc[0][0], 0, 0, 0);
        acc[0][1] = __builtin_amdgcn_mfma_f32_16x16x32_f16(a0, b1, acc[0][1], 0, 0, 0);
        acc[1][0] = __builtin_amdgcn_mfma_f32_16x16x32_f16(a1, b0, acc[1][0], 0, 0, 0);
        acc[1][1] = __builtin_amdgcn_mfma_f32_16x16x32_f16(a1, b1, acc[1][1], 0, 0, 0);
        __syncthreads();
    }

    // ---- epilogue: D[row = quad*4+r][col = l15] per 16x16 tile
#pragma unroll
    for (int tm = 0; tm < 2; tm++)
#pragma unroll
    for (int tn = 0; tn < 2; tn++) {
#pragma unroll
        for (int r = 0; r < 4; r++) {
            int gr = m0 + wm + tm * 16 + quad * 4 + r;
            int gc = n0 + wn + tn * 16 + l15;
            float v = acc[tm][tn][r] * alpha;
            if (HAS_BIAS) v += bias[gr];
            long idx = (long)b * sCb + (long)gr * N + gc;
            if (HAS_RESID) v += resid[idx];
            if (OUT_F32) ((float*)Cp_)[idx] = v;
            else         ((f16*)Cp_)[idx] = (f16)v;
        }
    }
}

extern "C" void kernel_launch(void* const* d_in, const int* in_sizes, int n_in,
                              void* d_out, int out_size, void* d_ws, size_t ws_size,
                              hipStream_t stream)
{
    const float* x      = (const float*)d_in[0];
    const float* gamma  = (const float*)d_in[1];
    const float* beta   = (const float*)d_in[2];
    const float* w_qkv  = (const float*)d_in[3];
    const float* b_qkv  = (const float*)d_in[4];
    const float* w_proj = (const float*)d_in[5];
    const float* b_proj = (const float*)d_in[6];
    float* out = (float*)d_out;

    char* ws = (char*)d_ws;
    f16* xn   = (f16*)(ws);                                  // 16 MB : [16][512][1024]
    f16* qkv  = (f16*)(ws + 16777216);                       // 48 MB : [16][1536][1024]
    f16* S    = (f16*)(ws + 16777216 + 50331648);            // 32 MB : [16][1024][1024]
    f16* aout = (f16*)(ws + 16777216 + 50331648 + 33554432); // 16 MB : [16][512][1024]

    // 1) GroupNorm
    groupnorm_kernel<<<512, 256, 0, stream>>>(x, gamma, beta, xn);

    // 2) QKV GEMM: qkv[b][o][hw] = sum_c W[o][c] * xn[b][c][hw] + b_qkv[o]
    gemm_mfma<true, false, false, false, true, false><<<dim3(16, 24, 16), 256, 0, stream>>>(
        w_qkv, xn, qkv, b_qkv, nullptr, 1.0f,
        1536, 1024, 512, /*lda*/512, /*ldb*/1024,
        0L, 512L * 1024, 1536L * 1024);

    // 3) Scores: S[b][i][j] = scale * sum_c q[b][c][i] * k[b][c][j]   (A = q stored [K=c][M=i])
    gemm_mfma<false, true, false, false, false, false><<<dim3(16, 16, 16), 256, 0, stream>>>(
        qkv, qkv + 512 * 1024, S, nullptr, nullptr, 0.04419417382415922f,
        1024, 1024, 512, /*lda*/1024, /*ldb*/1024,
        1536L * 1024, 1536L * 1024, 1024L * 1024);

    // 4) Softmax over j
    softmax_kernel<<<4096, 256, 0, stream>>>(S);

    // 5) PV: aout[b][c][i] = sum_j v[b][c][j] * P[b][i][j]   (B = P stored [N=i][K=j])
    gemm_mfma<false, false, true, false, false, false><<<dim3(16, 8, 16), 256, 0, stream>>>(
        qkv + 1024 * 1024, S, aout, nullptr, nullptr, 1.0f,
        512, 1024, 1024, /*lda*/1024, /*ldb*/1024,
        1536L * 1024, 1024L * 1024, 512L * 1024);

    // 6) Proj + bias + residual -> fp32 out
    gemm_mfma<true, false, false, true, true, true><<<dim3(16, 8, 16), 256, 0, stream>>>(
        w_proj, aout, out, b_proj, x, 1.0f,
        512, 1024, 512, /*lda*/512, /*ldb*/1024,
        0L, 512L * 1024, 512L * 1024);
}

// Round 2
// 284.634 us; speedup vs baseline: 1.5760x; 1.5760x over previous
//
#include <hip/hip_runtime.h>

// SelfAttention: GN -> 1x1 QKV -> softmax attention (HW=1024) -> 1x1 proj + residual
// B=16, C=512, HW=1024, GROUPS=32, EPS=1e-5, scale=C^-0.5
//
// Round 2: transpose-free GEMM layouts. All intermediates stored [free][K] so every
// GEMM stages with direct vector copies (no LDS transpose -> no 32-way bank conflicts).
//   xnT    [b][hw][c]    f16   (GN writes transposed via LDS bounce)
//   qkT    [b][hw][1024] f16   (cols 0..511 = q, 512..1023 = k)
//   v      [b][c][hw]    f16   (QKV epilogue writes v-part transposed, f16x4 chunks)
//   S/P    [b][i][j]     f16
//   attoutT[b][hw][c]    f16
// Tiles: BM=128 x BN=64, BK=32, 4 waves (each 64x32 -> acc[4][2] of 16x16x32 f16 MFMA).

typedef _Float16 f16;
typedef _Float16 f16x8 __attribute__((ext_vector_type(8)));
typedef _Float16 f16x4 __attribute__((ext_vector_type(4)));
typedef float fx4 __attribute__((ext_vector_type(4)));

#define BM 128
#define BN 64
#define BK 32
#define LDK 40   // 80B rows = 20 dwords: bank-uniform for b128 staging/frag access

// ---------------- GroupNorm: x fp32 [16][512][1024] -> xnT f16 [16][1024][512] ----------------
__global__ __launch_bounds__(256)
void groupnorm_kernel(const float* __restrict__ x, const float* __restrict__ gamma,
                      const float* __restrict__ beta, f16* __restrict__ xnT)
{
    __shared__ float red[256], red2[256];
    __shared__ float mu_s, rs_s;
    __shared__ __align__(16) f16 T[16][520];   // [ch][hw-half], padded: conflict-free scalar reads
    const int blk = blockIdx.x;                // b*32 + g
    const int b = blk >> 5, g = blk & 31;
    const long base = (long)blk * (16 * 1024); // 16 channels * 1024 spatial
    const int tid = threadIdx.x;
    const float4* xv = (const float4*)(x + base);

    float s = 0.f, s2 = 0.f;
#pragma unroll
    for (int i = 0; i < 16; i++) {
        float4 v = xv[tid + i * 256];
        s  += v.x + v.y + v.z + v.w;
        s2 += v.x * v.x + v.y * v.y + v.z * v.z + v.w * v.w;
    }
    red[tid] = s; red2[tid] = s2;
    __syncthreads();
    for (int off = 128; off > 0; off >>= 1) {
        if (tid < off) { red[tid] += red[tid + off]; red2[tid] += red2[tid + off]; }
        __syncthreads();
    }
    if (tid == 0) {
        float mu = red[0] * (1.f / 16384.f);
        float var = red2[0] * (1.f / 16384.f) - mu * mu;
        mu_s = mu;
        rs_s = rsqrtf(var + 1e-5f);
    }
    __syncthreads();
    const float mu = mu_s, rs = rs_s;

    for (int h = 0; h < 2; h++) {
        if (h) __syncthreads();                 // protect T reuse
        // stage half: 16 ch x 512 hw normalized into T
#pragma unroll
        for (int i = 0; i < 8; i++) {
            int idx = tid + i * 256;            // 0..2047
            int ch = idx >> 7;                  // 0..15
            int p4 = idx & 127;
            float4 v = *(const float4*)(x + base + ch * 1024 + h * 512 + p4 * 4);
            float gm = gamma[g * 16 + ch] * rs;
            float bt = beta[g * 16 + ch] - mu * gm;
            f16x4 o;
            o[0] = (f16)(v.x * gm + bt);
            o[1] = (f16)(v.y * gm + bt);
            o[2] = (f16)(v.z * gm + bt);
            o[3] = (f16)(v.w * gm + bt);
            *(f16x4*)&T[ch][p4 * 4] = o;
        }
        __syncthreads();
        // write out transposed: xnT[b][h*512+hw][g*16 + 0..15], 16B per thread-chunk
#pragma unroll
        for (int i = 0; i < 4; i++) {
            int idx = tid + i * 256;            // 0..1023
            int hw = idx >> 1;
            int half8 = (idx & 1) * 8;
            f16x8 o;
#pragma unroll
            for (int j = 0; j < 8; j++) o[j] = T[half8 + j][hw];
            long dst = ((long)b * 1024 + h * 512 + hw) * 512 + g * 16 + half8;
            *(f16x8*)(xnT + dst) = o;
        }
    }
}

// ---------------- Row softmax over j: S f16 [16][1024][1024], one wave per row ----------------
__global__ __launch_bounds__(256)
void softmax_kernel(f16* __restrict__ S)
{
    const int wid = blockIdx.x * 4 + (threadIdx.x >> 6);
    const int lane = threadIdx.x & 63;
    f16* p = S + (long)wid * 1024 + lane * 16;
    f16x8 h0 = *(const f16x8*)p;
    f16x8 h1 = *(const f16x8*)(p + 8);
    float v[16];
#pragma unroll
    for (int i = 0; i < 8; i++) { v[i] = (float)h0[i]; v[8 + i] = (float)h1[i]; }
    float mx = v[0];
#pragma unroll
    for (int i = 1; i < 16; i++) mx = fmaxf(mx, v[i]);
    for (int off = 32; off > 0; off >>= 1) mx = fmaxf(mx, __shfl_xor(mx, off, 64));
    float sum = 0.f;
#pragma unroll
    for (int i = 0; i < 16; i++) { v[i] = __expf(v[i] - mx); sum += v[i]; }
    for (int off = 32; off > 0; off >>= 1) sum += __shfl_xor(sum, off, 64);
    const float inv = 1.f / sum;
#pragma unroll
    for (int i = 0; i < 8; i++) { h0[i] = (f16)(v[i] * inv); h1[i] = (f16)(v[8 + i] * inv); }
    *(f16x8*)p = h0;
    *(f16x8*)(p + 8) = h1;
}

// ---------------- 128x64 MFMA GEMM, C[M][N] = alpha*A(MxK)*B(KxN)(+bias)(+resid) --------------
// A stored [M][K] (lda), B stored [N][K] (ldb) -- both staged with direct f16x8 copies.
// MODE 0: f16 out, C[m][n], ld=N, batch stride sCb.
// MODE 1: QKV split: n<1024 -> qkT[b][m][n] (ld 1024); n>=1024 -> C2 v[b][n-1024][m]; bias[n].
// MODE 2: fp32 out [m][n] ld=N + bias[m] + resid, batch stride sCb.
template<bool A_F32, bool B_F32, int MODE>
__global__ __launch_bounds__(256)
void gemm_kernel(const void* __restrict__ Ap, const void* __restrict__ Bp,
                 void* __restrict__ Cp, f16* __restrict__ C2p,
                 const float* __restrict__ bias, const float* __restrict__ resid,
                 float alpha, int M, int N, int K, int lda, int ldb,
                 long sAb, long sBb, long sCb)
{
    __shared__ __align__(16) f16 As[BM][LDK];
    __shared__ __align__(16) f16 Bs[BN][LDK];

    const int b = blockIdx.z;
    const int m0 = blockIdx.y * BM, n0 = blockIdx.x * BN;
    const int tid = threadIdx.x;
    const int wave = tid >> 6, lane = tid & 63;
    const int quad = lane >> 4, l15 = lane & 15;
    const int wm = (wave >> 1) * 64, wn = (wave & 1) * 32;

    fx4 acc[4][2] = {};

    for (int k0 = 0; k0 < K; k0 += BK) {
        // ---- stage A: 128 rows x 4 chunks = 512 chunks, 2 per thread
#pragma unroll
        for (int s = 0; s < 2; s++) {
            int idx = tid + s * 256;
            int row = idx >> 2;
            int c8 = (idx & 3) * 8;
            if (A_F32) {
                const float* A = (const float*)Ap + (long)b * sAb;
                const float* src = A + (long)(m0 + row) * lda + k0 + c8;
                float4 f0 = *(const float4*)src;
                float4 f1 = *(const float4*)(src + 4);
                f16x8 o;
                o[0]=(f16)f0.x; o[1]=(f16)f0.y; o[2]=(f16)f0.z; o[3]=(f16)f0.w;
                o[4]=(f16)f1.x; o[5]=(f16)f1.y; o[6]=(f16)f1.z; o[7]=(f16)f1.w;
                *(f16x8*)&As[row][c8] = o;
            } else {
                const f16* A = (const f16*)Ap + (long)b * sAb;
                *(f16x8*)&As[row][c8] = *(const f16x8*)(A + (long)(m0 + row) * lda + k0 + c8);
            }
        }
        // ---- stage B: 64 rows x 4 chunks = 256 chunks, 1 per thread
        {
            int row = tid >> 2;
            int c8 = (tid & 3) * 8;
            if (B_F32) {
                const float* B = (const float*)Bp + (long)b * sBb;
                const float* src = B + (long)(n0 + row) * ldb + k0 + c8;
                float4 f0 = *(const float4*)src;
                float4 f1 = *(const float4*)(src + 4);
                f16x8 o;
                o[0]=(f16)f0.x; o[1]=(f16)f0.y; o[2]=(f16)f0.z; o[3]=(f16)f0.w;
                o[4]=(f16)f1.x; o[5]=(f16)f1.y; o[6]=(f16)f1.z; o[7]=(f16)f1.w;
                *(f16x8*)&Bs[row][c8] = o;
            } else {
                const f16* B = (const f16*)Bp + (long)b * sBb;
                *(f16x8*)&Bs[row][c8] = *(const f16x8*)(B + (long)(n0 + row) * ldb + k0 + c8);
            }
        }
        __syncthreads();

        f16x8 bf[2];
#pragma unroll
        for (int tn = 0; tn < 2; tn++)
            bf[tn] = *(const f16x8*)&Bs[wn + tn * 16 + l15][quad * 8];
#pragma unroll
        for (int tm = 0; tm < 4; tm++) {
            f16x8 af = *(const f16x8*)&As[wm + tm * 16 + l15][quad * 8];
            acc[tm][0] = __builtin_amdgcn_mfma_f32_16x16x32_f16(af, bf[0], acc[tm][0], 0, 0, 0);
            acc[tm][1] = __builtin_amdgcn_mfma_f32_16x16x32_f16(af, bf[1], acc[tm][1], 0, 0, 0);
        }
        __syncthreads();
    }

    // ---- epilogue: D[row = quad*4+r][col = l15] per 16x16 tile
    if (MODE == 1 && n0 >= 1024) {
        // v-part: write transposed to C2 = v[b][c][hw], vectorized f16x4 along hw(=m)
#pragma unroll
        for (int tm = 0; tm < 4; tm++)
#pragma unroll
        for (int tn = 0; tn < 2; tn++) {
            int gc = n0 + wn + tn * 16 + l15;          // o index (>=1024)
            int gr0 = m0 + wm + tm * 16 + quad * 4;    // hw base
            float bs = bias[gc];
            f16x4 o;
#pragma unroll
            for (int r = 0; r < 4; r++) o[r] = (f16)(acc[tm][tn][r] + bs);
            *(f16x4*)(C2p + (long)b * 524288 + (long)(gc - 1024) * 1024 + gr0) = o;
        }
        return;
    }
#pragma unroll
    for (int tm = 0; tm < 4; tm++)
#pragma unroll
    for (int tn = 0; tn < 2; tn++) {
        int gc = n0 + wn + tn * 16 + l15;
#pragma unroll
        for (int r = 0; r < 4; r++) {
            int gr = m0 + wm + tm * 16 + quad * 4 + r;
            float v = acc[tm][tn][r] * alpha;
            if (MODE == 1) {
                v += bias[gc];
                ((f16*)Cp)[(long)b * 1048576 + (long)gr * 1024 + gc] = (f16)v;
            } else if (MODE == 2) {
                v += bias[gr];
                long idx = (long)b * sCb + (long)gr * N + gc;
                v += resid[idx];
                ((float*)Cp)[idx] = v;
            } else {
                ((f16*)Cp)[(long)b * sCb + (long)gr * N + gc] = (f16)v;
            }
        }
    }
}

extern "C" void kernel_launch(void* const* d_in, const int* in_sizes, int n_in,
                              void* d_out, int out_size, void* d_ws, size_t ws_size,
                              hipStream_t stream)
{
    const float* x      = (const float*)d_in[0];
    const float* gamma  = (const float*)d_in[1];
    const float* beta   = (const float*)d_in[2];
    const float* w_qkv  = (const float*)d_in[3];
    const float* b_qkv  = (const float*)d_in[4];
    const float* w_proj = (const float*)d_in[5];
    const float* b_proj = (const float*)d_in[6];
    float* out = (float*)d_out;

    char* ws = (char*)d_ws;
    f16* xnT   = (f16*)(ws);                     // 16 MB : [16][1024 hw][512 c]
    f16* qkT   = (f16*)(ws + (16L << 20));       // 32 MB : [16][1024 hw][1024 (q|k)]
    f16* vbuf  = (f16*)(ws + (48L << 20));       // 16 MB : [16][512 c][1024 hw]
    f16* S     = (f16*)(ws + (64L << 20));       // 32 MB : [16][1024 i][1024 j]
    f16* aoutT = (f16*)(ws + (96L << 20));       // 16 MB : [16][1024 hw][512 c]

    // 1) GroupNorm -> xnT
    groupnorm_kernel<<<512, 256, 0, stream>>>(x, gamma, beta, xnT);

    // 2) QKV: C[m=hw][n=o] = xnT[hw][c] . w_qkv[o][c]; q,k -> qkT, v -> vbuf (transposed)
    gemm_kernel<false, true, 1><<<dim3(24, 8, 16), 256, 0, stream>>>(
        xnT, w_qkv, qkT, vbuf, b_qkv, nullptr, 1.0f,
        1024, 1536, 512, /*lda*/512, /*ldb*/512,
        524288L, 0L, 0L);

    // 3) Scores: S[i][j] = scale * q[i][c] . k[j][c]
    gemm_kernel<false, false, 0><<<dim3(16, 8, 16), 256, 0, stream>>>(
        qkT, qkT + 512, S, nullptr, nullptr, nullptr, 0.04419417382415922f,
        1024, 1024, 512, /*lda*/1024, /*ldb*/1024,
        1048576L, 1048576L, 1048576L);

    // 4) Softmax over j
    softmax_kernel<<<4096, 256, 0, stream>>>(S);

    // 5) PV: aoutT[i][c] = P[i][j] . v[c][j]
    gemm_kernel<false, false, 0><<<dim3(8, 8, 16), 256, 0, stream>>>(
        S, vbuf, aoutT, nullptr, nullptr, nullptr, 1.0f,
        1024, 512, 1024, /*lda*/1024, /*ldb*/1024,
        1048576L, 524288L, 524288L);

    // 6) Proj: out[o][hw] = w_proj[o][c] . aoutT[hw][c] + b_proj[o] + x
    gemm_kernel<true, false, 2><<<dim3(16, 4, 16), 256, 0, stream>>>(
        w_proj, aoutT, out, nullptr, b_proj, x, 1.0f,
        512, 1024, 512, /*lda*/512, /*ldb*/512,
        0L, 524288L, 524288L);
}

// Round 3
// 268.842 us; speedup vs baseline: 1.6686x; 1.0587x over previous
//
#include <hip/hip_runtime.h>

// SelfAttention: GN -> 1x1 QKV -> softmax attention (HW=1024) -> 1x1 proj + residual
// B=16, C=512, HW=1024, GROUPS=32, EPS=1e-5, scale=C^-0.5
//
// Round 3: m97-style GEMM. 128x128 tiles, BK=32, global_load_lds width=16 staging with
// XOR chunk swizzle (coalesced global + conflict-free LDS frag reads), acc[4][4]/wave.
// w_qkv pre-converted fp32->f16 (stored in the S region, which is written only later).
// Layouts (all [free][K]):
//   xnT [b][hw][c], qkT [b][hw][q|k], v [b][c][hw], S/P [b][i][j], aoutT [b][hw][c]

typedef _Float16 f16;
typedef _Float16 f16x8 __attribute__((ext_vector_type(8)));
typedef _Float16 f16x4 __attribute__((ext_vector_type(4)));
typedef float fx4 __attribute__((ext_vector_type(4)));

__device__ __forceinline__ void gload16(const f16* g, f16* l) {
    __builtin_amdgcn_global_load_lds((const __attribute__((address_space(1))) void*)g,
                                     (__attribute__((address_space(3))) void*)l, 16, 0, 0);
}

// ---------------- weight convert: fp32 -> f16, n4 float4 chunks ----------------
__global__ __launch_bounds__(256)
void wconv_kernel(const float* __restrict__ w, f16* __restrict__ o, int n4)
{
    int i = blockIdx.x * 256 + threadIdx.x;
    if (i < n4) {
        float4 v = *(const float4*)(w + i * 4);
        f16x4 h;
        h[0] = (f16)v.x; h[1] = (f16)v.y; h[2] = (f16)v.z; h[3] = (f16)v.w;
        *(f16x4*)(o + i * 4) = h;
    }
}

// ---------------- GroupNorm: x fp32 [16][512][1024] -> xnT f16 [16][1024][512] ----------------
__global__ __launch_bounds__(256)
void groupnorm_kernel(const float* __restrict__ x, const float* __restrict__ gamma,
                      const float* __restrict__ beta, f16* __restrict__ xnT)
{
    __shared__ float red[256], red2[256];
    __shared__ float mu_s, rs_s;
    __shared__ __align__(16) f16 T[16][520];
    const int blk = blockIdx.x;                // b*32 + g
    const int b = blk >> 5, g = blk & 31;
    const long base = (long)blk * (16 * 1024);
    const int tid = threadIdx.x;
    const float4* xv = (const float4*)(x + base);

    float s = 0.f, s2 = 0.f;
#pragma unroll
    for (int i = 0; i < 16; i++) {
        float4 v = xv[tid + i * 256];
        s  += v.x + v.y + v.z + v.w;
        s2 += v.x * v.x + v.y * v.y + v.z * v.z + v.w * v.w;
    }
    red[tid] = s; red2[tid] = s2;
    __syncthreads();
    for (int off = 128; off > 0; off >>= 1) {
        if (tid < off) { red[tid] += red[tid + off]; red2[tid] += red2[tid + off]; }
        __syncthreads();
    }
    if (tid == 0) {
        float mu = red[0] * (1.f / 16384.f);
        float var = red2[0] * (1.f / 16384.f) - mu * mu;
        mu_s = mu;
        rs_s = rsqrtf(var + 1e-5f);
    }
    __syncthreads();
    const float mu = mu_s, rs = rs_s;

    for (int h = 0; h < 2; h++) {
        if (h) __syncthreads();
#pragma unroll
        for (int i = 0; i < 8; i++) {
            int idx = tid + i * 256;
            int ch = idx >> 7;
            int p4 = idx & 127;
            float4 v = *(const float4*)(x + base + ch * 1024 + h * 512 + p4 * 4);
            float gm = gamma[g * 16 + ch] * rs;
            float bt = beta[g * 16 + ch] - mu * gm;
            f16x4 o;
            o[0] = (f16)(v.x * gm + bt);
            o[1] = (f16)(v.y * gm + bt);
            o[2] = (f16)(v.z * gm + bt);
            o[3] = (f16)(v.w * gm + bt);
            *(f16x4*)&T[ch][p4 * 4] = o;
        }
        __syncthreads();
#pragma unroll
        for (int i = 0; i < 4; i++) {
            int idx = tid + i * 256;
            int hw = idx >> 1;
            int half8 = (idx & 1) * 8;
            f16x8 o;
#pragma unroll
            for (int j = 0; j < 8; j++) o[j] = T[half8 + j][hw];
            long dst = ((long)b * 1024 + h * 512 + hw) * 512 + g * 16 + half8;
            *(f16x8*)(xnT + dst) = o;
        }
    }
}

// ---------------- Row softmax over j: S f16 [16][1024][1024], one wave per row ----------------
__global__ __launch_bounds__(256)
void softmax_kernel(f16* __restrict__ S)
{
    const int wid = blockIdx.x * 4 + (threadIdx.x >> 6);
    const int lane = threadIdx.x & 63;
    f16* p = S + (long)wid * 1024 + lane * 16;
    f16x8 h0 = *(const f16x8*)p;
    f16x8 h1 = *(const f16x8*)(p + 8);
    float v[16];
#pragma unroll
    for (int i = 0; i < 8; i++) { v[i] = (float)h0[i]; v[8 + i] = (float)h1[i]; }
    float mx = v[0];
#pragma unroll
    for (int i = 1; i < 16; i++) mx = fmaxf(mx, v[i]);
    for (int off = 32; off > 0; off >>= 1) mx = fmaxf(mx, __shfl_xor(mx, off, 64));
    float sum = 0.f;
#pragma unroll
    for (int i = 0; i < 16; i++) { v[i] = __expf(v[i] - mx); sum += v[i]; }
    for (int off = 32; off > 0; off >>= 1) sum += __shfl_xor(sum, off, 64);
    const float inv = 1.f / sum;
#pragma unroll
    for (int i = 0; i < 8; i++) { h0[i] = (f16)(v[i] * inv); h1[i] = (f16)(v[8 + i] * inv); }
    *(f16x8*)p = h0;
    *(f16x8*)(p + 8) = h1;
}

// ---------------- 128x128 MFMA GEMM, C[M][N] = alpha*A(MxK)*B(KxN)(+bias)(+resid) -------------
// A stored [M][K] f16 (async staged) unless A_F32 (proj weights, manual staging+convert).
// B stored [N][K] f16, async staged.
// LDS layout (both As/Bs): [row][chunk] with chunk' = chunk ^ (row&3), 16B chunks, BK=32.
// MODE 0: f16 out C[m][n] ld=N, batch stride sCb, *alpha.
// MODE 1: QKV split: n0<1024 -> qkT[b][m][n] (ld 1024); n0>=1024 -> v[b][n-1024][m]; bias[n].
// MODE 2: fp32 out [m][n] ld=N + bias[m] + resid, batch stride sCb.
template<bool A_F32, int MODE>
__global__ __launch_bounds__(256)
void gemm_kernel(const void* __restrict__ Ap, const f16* __restrict__ Bp,
                 void* __restrict__ Cp, f16* __restrict__ C2p,
                 const float* __restrict__ bias, const float* __restrict__ resid,
                 float alpha, int M, int N, int K, int lda, int ldb,
                 long sAb, long sBb, long sCb)
{
    __shared__ __align__(16) f16 As[128 * 32];
    __shared__ __align__(16) f16 Bs[128 * 32];

    const int b = blockIdx.z;
    const int m0 = blockIdx.y * 128, n0 = blockIdx.x * 128;
    const int tid = threadIdx.x;
    const int wave = tid >> 6, lane = tid & 63;
    const int quad = lane >> 4, l15 = lane & 15;
    const int wm = (wave >> 1) * 64, wn = (wave & 1) * 64;
    const int chunkoff = (quad ^ (l15 & 3)) * 8;   // loop-invariant frag chunk (XOR swizzle)

    const f16* Ag = (const f16*)Ap + (A_F32 ? 0L : (long)b * sAb);
    const float* Ag32 = (const float*)Ap;
    const f16* Bg = Bp + (long)b * sBb;

    const int si = lane >> 2;   // row within a 16-row staging instr
    const int sj = lane & 3;    // chunk slot

    fx4 acc[4][4] = {};

    for (int k0 = 0; k0 < K; k0 += 32) {
        if (A_F32) {
            // manual staging with convert, same swizzled LDS layout
#pragma unroll
            for (int s = 0; s < 2; s++) {
                int idx = tid + s * 256;
                int row = idx >> 2, j = idx & 3;
                int gj = j ^ (row & 3);
                const float* src = Ag32 + (long)(m0 + row) * lda + k0 + gj * 8;
                float4 f0 = *(const float4*)src;
                float4 f1 = *(const float4*)(src + 4);
                f16x8 o;
                o[0]=(f16)f0.x; o[1]=(f16)f0.y; o[2]=(f16)f0.z; o[3]=(f16)f0.w;
                o[4]=(f16)f1.x; o[5]=(f16)f1.y; o[6]=(f16)f1.z; o[7]=(f16)f1.w;
                *(f16x8*)&As[row * 32 + j * 8] = o;
            }
        } else {
#pragma unroll
            for (int s = 0; s < 2; s++) {
                int R = wave * 32 + s * 16;
                int row = R + si;
                gload16(Ag + (long)(m0 + row) * lda + k0 + ((sj ^ (row & 3)) * 8),
                        &As[R * 32]);
            }
        }
#pragma unroll
        for (int s = 0; s < 2; s++) {
            int R = wave * 32 + s * 16;
            int row = R + si;
            gload16(Bg + (long)(n0 + row) * ldb + k0 + ((sj ^ (row & 3)) * 8),
                    &Bs[R * 32]);
        }
        __syncthreads();

        f16x8 bf[4];
#pragma unroll
        for (int tn = 0; tn < 4; tn++)
            bf[tn] = *(const f16x8*)&Bs[(wn + tn * 16 + l15) * 32 + chunkoff];
#pragma unroll
        for (int tm = 0; tm < 4; tm++) {
            f16x8 af = *(const f16x8*)&As[(wm + tm * 16 + l15) * 32 + chunkoff];
#pragma unroll
            for (int tn = 0; tn < 4; tn++)
                acc[tm][tn] = __builtin_amdgcn_mfma_f32_16x16x32_f16(af, bf[tn], acc[tm][tn], 0, 0, 0);
        }
        __syncthreads();
    }

    // ---- epilogue: D[row = quad*4+r][col = l15] per 16x16 tile
    if (MODE == 1 && n0 >= 1024) {
        // v-part: write transposed to v[b][c][hw], vectorized f16x4 along hw(=m)
#pragma unroll
        for (int tm = 0; tm < 4; tm++)
#pragma unroll
        for (int tn = 0; tn < 4; tn++) {
            int gc = n0 + wn + tn * 16 + l15;
            int gr0 = m0 + wm + tm * 16 + quad * 4;
            float bs = bias[gc];
            f16x4 o;
#pragma unroll
            for (int r = 0; r < 4; r++) o[r] = (f16)(acc[tm][tn][r] + bs);
            *(f16x4*)(C2p + (long)b * 524288 + (long)(gc - 1024) * 1024 + gr0) = o;
        }
        return;
    }
#pragma unroll
    for (int tm = 0; tm < 4; tm++)
#pragma unroll
    for (int tn = 0; tn < 4; tn++) {
        int gc = n0 + wn + tn * 16 + l15;
#pragma unroll
        for (int r = 0; r < 4; r++) {
            int gr = m0 + wm + tm * 16 + quad * 4 + r;
            float v = acc[tm][tn][r] * alpha;
            if (MODE == 1) {
                v += bias[gc];
                ((f16*)Cp)[(long)b * 1048576 + (long)gr * 1024 + gc] = (f16)v;
            } else if (MODE == 2) {
                v += bias[gr];
                long idx = (long)b * sCb + (long)gr * N + gc;
                v += resid[idx];
                ((float*)Cp)[idx] = v;
            } else {
                ((f16*)Cp)[(long)b * sCb + (long)gr * N + gc] = (f16)v;
            }
        }
    }
}

extern "C" void kernel_launch(void* const* d_in, const int* in_sizes, int n_in,
                              void* d_out, int out_size, void* d_ws, size_t ws_size,
                              hipStream_t stream)
{
    const float* x      = (const float*)d_in[0];
    const float* gamma  = (const float*)d_in[1];
    const float* beta   = (const float*)d_in[2];
    const float* w_qkv  = (const float*)d_in[3];
    const float* b_qkv  = (const float*)d_in[4];
    const float* w_proj = (const float*)d_in[5];
    const float* b_proj = (const float*)d_in[6];
    float* out = (float*)d_out;

    char* ws = (char*)d_ws;
    f16* xnT   = (f16*)(ws);                 // 16 MB : [16][1024 hw][512 c]
    f16* qkT   = (f16*)(ws + (16L << 20));   // 32 MB : [16][1024 hw][1024 (q|k)]
    f16* vbuf  = (f16*)(ws + (48L << 20));   // 16 MB : [16][512 c][1024 hw]
    f16* S     = (f16*)(ws + (64L << 20));   // 32 MB : [16][1024 i][1024 j]
    f16* aoutT = (f16*)(ws + (96L << 20));   // 16 MB : [16][1024 hw][512 c]
    f16* wqkvh = S;                          // 1.5 MB, dead before scores writes S

    // 0) convert w_qkv fp32 -> f16 (into S region; scores overwrites it later)
    wconv_kernel<<<768, 256, 0, stream>>>(w_qkv, wqkvh, 196608);

    // 1) GroupNorm -> xnT
    groupnorm_kernel<<<512, 256, 0, stream>>>(x, gamma, beta, xnT);

    // 2) QKV: C[m=hw][n=o] = xnT[hw][c] . w_qkv[o][c]; q,k -> qkT, v -> vbuf (transposed)
    gemm_kernel<false, 1><<<dim3(12, 8, 16), 256, 0, stream>>>(
        xnT, wqkvh, qkT, vbuf, b_qkv, nullptr, 1.0f,
        1024, 1536, 512, /*lda*/512, /*ldb*/512,
        524288L, 0L, 0L);

    // 3) Scores: S[i][j] = scale * q[i][c] . k[j][c]
    gemm_kernel<false, 0><<<dim3(8, 8, 16), 256, 0, stream>>>(
        qkT, qkT + 512, S, nullptr, nullptr, nullptr, 0.04419417382415922f,
        1024, 1024, 512, /*lda*/1024, /*ldb*/1024,
        1048576L, 1048576L, 1048576L);

    // 4) Softmax over j
    softmax_kernel<<<4096, 256, 0, stream>>>(S);

    // 5) PV: aoutT[i][c] = P[i][j] . v[c][j]
    gemm_kernel<false, 0><<<dim3(4, 8, 16), 256, 0, stream>>>(
        S, vbuf, aoutT, nullptr, nullptr, nullptr, 1.0f,
        1024, 512, 1024, /*lda*/1024, /*ldb*/1024,
        1048576L, 524288L, 524288L);

    // 6) Proj: out[o][hw] = w_proj[o][c] . aoutT[hw][c] + b_proj[o] + x
    gemm_kernel<true, 2><<<dim3(8, 4, 16), 256, 0, stream>>>(
        w_proj, aoutT, out, nullptr, b_proj, x, 1.0f,
        512, 1024, 512, /*lda*/512, /*ldb*/512,
        0L, 524288L, 524288L);
}

// Round 4
// 249.941 us; speedup vs baseline: 1.7948x; 1.0756x over previous
//
#include <hip/hip_runtime.h>

// SelfAttention: GN -> 1x1 QKV -> softmax attention (HW=1024) -> 1x1 proj + residual
// B=16, C=512, HW=1024, GROUPS=32, EPS=1e-5, scale=C^-0.5
//
// Round 4: double-buffered K-loop (stage k+1 into alt LDS buffer, then compute k).
// The compiler's vmcnt(0)-before-barrier now waits on loads issued a full compute-phase
// earlier -> per-iter wall ~= max(latency-compute,0)+compute instead of latency+compute.
// Both weights pre-converted to f16 so all GEMM staging is async global_load_lds w16
// with XOR chunk swizzle. Layouts (all [free][K]):
//   xnT [b][hw][c], qkT [b][hw][q|k], v [b][c][hw], S/P [b][i][j], aoutT [b][hw][c]

typedef _Float16 f16;
typedef _Float16 f16x8 __attribute__((ext_vector_type(8)));
typedef _Float16 f16x4 __attribute__((ext_vector_type(4)));
typedef float fx4 __attribute__((ext_vector_type(4)));

__device__ __forceinline__ void gload16(const f16* g, f16* l) {
    __builtin_amdgcn_global_load_lds((const __attribute__((address_space(1))) void*)g,
                                     (__attribute__((address_space(3))) void*)l, 16, 0, 0);
}

// ---------------- weight convert: fp32 -> f16, n4 float4 chunks ----------------
__global__ __launch_bounds__(256)
void wconv_kernel(const float* __restrict__ w, f16* __restrict__ o, int n4)
{
    int i = blockIdx.x * 256 + threadIdx.x;
    if (i < n4) {
        float4 v = *(const float4*)(w + i * 4);
        f16x4 h;
        h[0] = (f16)v.x; h[1] = (f16)v.y; h[2] = (f16)v.z; h[3] = (f16)v.w;
        *(f16x4*)(o + i * 4) = h;
    }
}

// ---------------- GroupNorm: x fp32 [16][512][1024] -> xnT f16 [16][1024][512] ----------------
__global__ __launch_bounds__(256)
void groupnorm_kernel(const float* __restrict__ x, const float* __restrict__ gamma,
                      const float* __restrict__ beta, f16* __restrict__ xnT)
{
    __shared__ float red[256], red2[256];
    __shared__ float mu_s, rs_s;
    __shared__ __align__(16) f16 T[16][520];
    const int blk = blockIdx.x;                // b*32 + g
    const int b = blk >> 5, g = blk & 31;
    const long base = (long)blk * (16 * 1024);
    const int tid = threadIdx.x;
    const float4* xv = (const float4*)(x + base);

    float s = 0.f, s2 = 0.f;
#pragma unroll
    for (int i = 0; i < 16; i++) {
        float4 v = xv[tid + i * 256];
        s  += v.x + v.y + v.z + v.w;
        s2 += v.x * v.x + v.y * v.y + v.z * v.z + v.w * v.w;
    }
    red[tid] = s; red2[tid] = s2;
    __syncthreads();
    for (int off = 128; off > 0; off >>= 1) {
        if (tid < off) { red[tid] += red[tid + off]; red2[tid] += red2[tid + off]; }
        __syncthreads();
    }
    if (tid == 0) {
        float mu = red[0] * (1.f / 16384.f);
        float var = red2[0] * (1.f / 16384.f) - mu * mu;
        mu_s = mu;
        rs_s = rsqrtf(var + 1e-5f);
    }
    __syncthreads();
    const float mu = mu_s, rs = rs_s;

    for (int h = 0; h < 2; h++) {
        if (h) __syncthreads();
#pragma unroll
        for (int i = 0; i < 8; i++) {
            int idx = tid + i * 256;
            int ch = idx >> 7;
            int p4 = idx & 127;
            float4 v = *(const float4*)(x + base + ch * 1024 + h * 512 + p4 * 4);
            float gm = gamma[g * 16 + ch] * rs;
            float bt = beta[g * 16 + ch] - mu * gm;
            f16x4 o;
            o[0] = (f16)(v.x * gm + bt);
            o[1] = (f16)(v.y * gm + bt);
            o[2] = (f16)(v.z * gm + bt);
            o[3] = (f16)(v.w * gm + bt);
            *(f16x4*)&T[ch][p4 * 4] = o;
        }
        __syncthreads();
#pragma unroll
        for (int i = 0; i < 4; i++) {
            int idx = tid + i * 256;
            int hw = idx >> 1;
            int half8 = (idx & 1) * 8;
            f16x8 o;
#pragma unroll
            for (int j = 0; j < 8; j++) o[j] = T[half8 + j][hw];
            long dst = ((long)b * 1024 + h * 512 + hw) * 512 + g * 16 + half8;
            *(f16x8*)(xnT + dst) = o;
        }
    }
}

// ---------------- Row softmax over j: S f16 [16][1024][1024], one wave per row ----------------
__global__ __launch_bounds__(256)
void softmax_kernel(f16* __restrict__ S)
{
    const int wid = blockIdx.x * 4 + (threadIdx.x >> 6);
    const int lane = threadIdx.x & 63;
    f16* p = S + (long)wid * 1024 + lane * 16;
    f16x8 h0 = *(const f16x8*)p;
    f16x8 h1 = *(const f16x8*)(p + 8);
    float v[16];
#pragma unroll
    for (int i = 0; i < 8; i++) { v[i] = (float)h0[i]; v[8 + i] = (float)h1[i]; }
    float mx = v[0];
#pragma unroll
    for (int i = 1; i < 16; i++) mx = fmaxf(mx, v[i]);
    for (int off = 32; off > 0; off >>= 1) mx = fmaxf(mx, __shfl_xor(mx, off, 64));
    float sum = 0.f;
#pragma unroll
    for (int i = 0; i < 16; i++) { v[i] = __expf(v[i] - mx); sum += v[i]; }
    for (int off = 32; off > 0; off >>= 1) sum += __shfl_xor(sum, off, 64);
    const float inv = 1.f / sum;
#pragma unroll
    for (int i = 0; i < 8; i++) { h0[i] = (f16)(v[i] * inv); h1[i] = (f16)(v[8 + i] * inv); }
    *(f16x8*)p = h0;
    *(f16x8*)(p + 8) = h1;
}

// ---------------- 128x128 MFMA GEMM, C[M][N] = alpha*A(MxK)*B(KxN)(+bias)(+resid) -------------
// A stored [M][K] f16 (lda), B stored [N][K] f16 (ldb); both async-staged, double-buffered.
// LDS layout: [row][chunk], chunk' = chunk ^ (row&3) (XOR swizzle), 16B chunks, BK=32.
// MODE 0: f16 out C[m][n] ld=N, batch stride sCb, *alpha.
// MODE 1: QKV split: n0<1024 -> qkT[b][m][n] (ld 1024); n0>=1024 -> v[b][n-1024][m]; bias[n].
// MODE 2: fp32 out [m][n] ld=N + bias[m] + resid, batch stride sCb.
template<int MODE>
__global__ __launch_bounds__(256)
void gemm_kernel(const f16* __restrict__ Ap, const f16* __restrict__ Bp,
                 void* __restrict__ Cp, f16* __restrict__ C2p,
                 const float* __restrict__ bias, const float* __restrict__ resid,
                 float alpha, int M, int N, int K, int lda, int ldb,
                 long sAb, long sBb, long sCb)
{
    __shared__ __align__(16) f16 As[2][128 * 32];
    __shared__ __align__(16) f16 Bs[2][128 * 32];

    const int b = blockIdx.z;
    const int m0 = blockIdx.y * 128, n0 = blockIdx.x * 128;
    const int tid = threadIdx.x;
    const int wave = tid >> 6, lane = tid & 63;
    const int quad = lane >> 4, l15 = lane & 15;
    const int wm = (wave >> 1) * 64, wn = (wave & 1) * 64;
    const int chunkoff = (quad ^ (l15 & 3)) * 8;   // loop-invariant frag chunk (XOR swizzle)

    const f16* Ag = Ap + (long)b * sAb;
    const f16* Bg = Bp + (long)b * sBb;

    const int si = lane >> 2;   // row within a 16-row staging instr
    const int sj = lane & 3;    // chunk slot

    // per-wave staging addresses (row part); global chunk = sj ^ (row&3)
    const int R0 = wave * 32, R1 = wave * 32 + 16;
    const f16* agA0 = Ag + (long)(m0 + R0 + si) * lda + ((sj ^ ((R0 + si) & 3)) * 8);
    const f16* agA1 = Ag + (long)(m0 + R1 + si) * lda + ((sj ^ ((R1 + si) & 3)) * 8);
    const f16* agB0 = Bg + (long)(n0 + R0 + si) * ldb + ((sj ^ ((R0 + si) & 3)) * 8);
    const f16* agB1 = Bg + (long)(n0 + R1 + si) * ldb + ((sj ^ ((R1 + si) & 3)) * 8);

    fx4 acc[4][4] = {};

    const int nIter = K >> 5;
    // prologue: stage tile 0 into buffer 0
    gload16(agA0, &As[0][R0 * 32]);
    gload16(agA1, &As[0][R1 * 32]);
    gload16(agB0, &Bs[0][R0 * 32]);
    gload16(agB1, &Bs[0][R1 * 32]);

    for (int it = 0; it < nIter; ++it) {
        __syncthreads();           // drains staging of tile `it` (+ prev compute's LDS reads)
        const int cur = it & 1;
        if (it + 1 < nIter) {
            const int k = (it + 1) << 5;
            gload16(agA0 + k, &As[cur ^ 1][R0 * 32]);
            gload16(agA1 + k, &As[cur ^ 1][R1 * 32]);
            gload16(agB0 + k, &Bs[cur ^ 1][R0 * 32]);
            gload16(agB1 + k, &Bs[cur ^ 1][R1 * 32]);
        }
        f16x8 bf[4];
#pragma unroll
        for (int tn = 0; tn < 4; tn++)
            bf[tn] = *(const f16x8*)&Bs[cur][(wn + tn * 16 + l15) * 32 + chunkoff];
#pragma unroll
        for (int tm = 0; tm < 4; tm++) {
            f16x8 af = *(const f16x8*)&As[cur][(wm + tm * 16 + l15) * 32 + chunkoff];
#pragma unroll
            for (int tn = 0; tn < 4; tn++)
                acc[tm][tn] = __builtin_amdgcn_mfma_f32_16x16x32_f16(af, bf[tn], acc[tm][tn], 0, 0, 0);
        }
    }

    // ---- epilogue: D[row = quad*4+r][col = l15] per 16x16 tile
    if (MODE == 1 && n0 >= 1024) {
        // v-part: write transposed to v[b][c][hw], vectorized f16x4 along hw(=m)
#pragma unroll
        for (int tm = 0; tm < 4; tm++)
#pragma unroll
        for (int tn = 0; tn < 4; tn++) {
            int gc = n0 + wn + tn * 16 + l15;
            int gr0 = m0 + wm + tm * 16 + quad * 4;
            float bs = bias[gc];
            f16x4 o;
#pragma unroll
            for (int r = 0; r < 4; r++) o[r] = (f16)(acc[tm][tn][r] + bs);
            *(f16x4*)(C2p + (long)b * 524288 + (long)(gc - 1024) * 1024 + gr0) = o;
        }
        return;
    }
#pragma unroll
    for (int tm = 0; tm < 4; tm++)
#pragma unroll
    for (int tn = 0; tn < 4; tn++) {
        int gc = n0 + wn + tn * 16 + l15;
#pragma unroll
        for (int r = 0; r < 4; r++) {
            int gr = m0 + wm + tm * 16 + quad * 4 + r;
            float v = acc[tm][tn][r] * alpha;
            if (MODE == 1) {
                v += bias[gc];
                ((f16*)Cp)[(long)b * 1048576 + (long)gr * 1024 + gc] = (f16)v;
            } else if (MODE == 2) {
                v += bias[gr];
                long idx = (long)b * sCb + (long)gr * N + gc;
                v += resid[idx];
                ((float*)Cp)[idx] = v;
            } else {
                ((f16*)Cp)[(long)b * sCb + (long)gr * N + gc] = (f16)v;
            }
        }
    }
}

extern "C" void kernel_launch(void* const* d_in, const int* in_sizes, int n_in,
                              void* d_out, int out_size, void* d_ws, size_t ws_size,
                              hipStream_t stream)
{
    const float* x      = (const float*)d_in[0];
    const float* gamma  = (const float*)d_in[1];
    const float* beta   = (const float*)d_in[2];
    const float* w_qkv  = (const float*)d_in[3];
    const float* b_qkv  = (const float*)d_in[4];
    const float* w_proj = (const float*)d_in[5];
    const float* b_proj = (const float*)d_in[6];
    float* out = (float*)d_out;

    char* ws = (char*)d_ws;
    f16* xnT   = (f16*)(ws);                 // 16 MB : [16][1024 hw][512 c]
    f16* qkT   = (f16*)(ws + (16L << 20));   // 32 MB : [16][1024 hw][1024 (q|k)]
    f16* vbuf  = (f16*)(ws + (48L << 20));   // 16 MB : [16][512 c][1024 hw]
    f16* S     = (f16*)(ws + (64L << 20));   // 32 MB : [16][1024 i][1024 j]
    f16* aoutT = (f16*)(ws + (96L << 20));   // 16 MB : [16][1024 hw][512 c]
    f16* wqkvh = S;                          // 1.5 MB; dead before scores writes S
    f16* wprjh = xnT;                        // 0.5 MB; written after QKV consumes xnT

    // 0) convert w_qkv fp32 -> f16 (into S region; scores overwrites later)
    wconv_kernel<<<768, 256, 0, stream>>>(w_qkv, wqkvh, 196608);

    // 1) GroupNorm -> xnT
    groupnorm_kernel<<<512, 256, 0, stream>>>(x, gamma, beta, xnT);

    // 2) QKV: C[m=hw][n=o] = xnT[hw][c] . w_qkv[o][c]; q,k -> qkT, v -> vbuf (transposed)
    gemm_kernel<1><<<dim3(12, 8, 16), 256, 0, stream>>>(
        xnT, wqkvh, qkT, vbuf, b_qkv, nullptr, 1.0f,
        1024, 1536, 512, /*lda*/512, /*ldb*/512,
        524288L, 0L, 0L);

    // 2b) convert w_proj fp32 -> f16 into xnT region (xnT dead after QKV)
    wconv_kernel<<<256, 256, 0, stream>>>(w_proj, wprjh, 65536);

    // 3) Scores: S[i][j] = scale * q[i][c] . k[j][c]
    gemm_kernel<0><<<dim3(8, 8, 16), 256, 0, stream>>>(
        qkT, qkT + 512, S, nullptr, nullptr, nullptr, 0.04419417382415922f,
        1024, 1024, 512, /*lda*/1024, /*ldb*/1024,
        1048576L, 1048576L, 1048576L);

    // 4) Softmax over j
    softmax_kernel<<<4096, 256, 0, stream>>>(S);

    // 5) PV: aoutT[i][c] = P[i][j] . v[c][j]
    gemm_kernel<0><<<dim3(4, 8, 16), 256, 0, stream>>>(
        S, vbuf, aoutT, nullptr, nullptr, nullptr, 1.0f,
        1024, 512, 1024, /*lda*/1024, /*ldb*/1024,
        1048576L, 524288L, 524288L);

    // 6) Proj: out[o][hw] = w_proj[o][c] . aoutT[hw][c] + b_proj[o] + x
    gemm_kernel<2><<<dim3(8, 4, 16), 256, 0, stream>>>(
        wprjh, aoutT, out, nullptr, b_proj, x, 1.0f,
        512, 1024, 512, /*lda*/512, /*ldb*/512,
        0L, 524288L, 524288L);
}